// Round 11
// baseline (228.453 us; speedup 1.0000x reference)
//
#include <hip/hip_runtime.h>

// ---------------------------------------------------------------------------
// Compile-time Wigner 3j (exact port of the reference Python, fp64)
// ---------------------------------------------------------------------------
struct CD { double re, im; };
constexpr CD cmul(CD a, CD b){ return CD{a.re*b.re - a.im*b.im, a.re*b.im + a.im*b.re}; }
constexpr CD conj_(CD a){ return CD{a.re, -a.im}; }

constexpr double factd(int n){ double r = 1.0; for(int i = 2; i <= n; ++i) r *= (double)i; return r; }
constexpr double csqrt_(double x){
  if (x <= 0.0) return 0.0;
  double g = x > 1.0 ? x : 1.0;
  for (int i = 0; i < 100; ++i) g = 0.5*(g + x/g);
  return g;
}

constexpr double su2_cg(int j1,int m1,int j2,int m2,int j3,int m3){
  if (m3 != m1 + m2) return 0.0;
  int vmin = -j1 + j2 + m3;
  if (-j1 + m1 > vmin) vmin = -j1 + m1;
  if (0 > vmin) vmin = 0;
  int vmax = j2 + j3 + m1;
  if (j3 - j1 + j2 < vmax) vmax = j3 - j1 + j2;
  if (j3 + m3 < vmax) vmax = j3 + m3;
  double c = csqrt_((2.0*j3 + 1.0) * factd(j3 + j1 - j2) * factd(j3 - j1 + j2) * factd(j1 + j2 - j3)
                    * factd(j3 + m3) * factd(j3 - m3)
                    / (factd(j1 + j2 + j3 + 1) * factd(j1 - m1) * factd(j1 + m1)
                       * factd(j2 - m2) * factd(j2 + m2)));
  double s = 0.0;
  for (int v = vmin; v <= vmax; ++v){
    double t = (((v + j2 + m2) & 1) ? -1.0 : 1.0) / factd(v)
               * factd(j2 + j3 + m1 - v) * factd(j1 - m1 + v)
               / factd(j3 - j1 + j2 - v) / factd(j3 + m3 - v) / factd(v + j1 - j2 - m3);
    s += t;
  }
  return c * s;
}

struct QM { CD m[7][7]; };
constexpr QM qmat(int l){
  QM q{};
  double is2 = 1.0 / csqrt_(2.0);
  for (int mm = -l; mm < 0; ++mm){
    q.m[l+mm][l-mm] = CD{is2, 0.0};
    q.m[l+mm][l+mm] = CD{0.0, -is2};
  }
  q.m[l][l] = CD{1.0, 0.0};
  for (int mm = 1; mm <= l; ++mm){
    double sgn = (mm & 1) ? -1.0 : 1.0;
    q.m[l+mm][l+mm] = CD{sgn*is2, 0.0};
    q.m[l+mm][l-mm] = CD{0.0, sgn*is2};
  }
  CD ph = (l % 4 == 0) ? CD{1,0} : (l % 4 == 1) ? CD{0,-1} : (l % 4 == 2) ? CD{-1,0} : CD{0,1};
  for (int r = 0; r < 7; ++r)
    for (int c = 0; c < 7; ++c)
      q.m[r][c] = cmul(ph, q.m[r][c]);
  return q;
}

template<int L1,int L2,int L3> struct W3JT { float v[2*L1+1][2*L2+1][2*L3+1]; };

template<int L1,int L2,int L3>
constexpr W3JT<L1,L2,L3> make_w3j(){
  constexpr int D1 = 2*L1+1, D2 = 2*L2+1, D3 = 2*L3+1;
  QM q1 = qmat(L1), q2 = qmat(L2), q3 = qmat(L3);
  double cg[7][7] = {};
  for (int i = 0; i < D1; ++i)
    for (int k = 0; k < D2; ++k){
      int n = i + k - L1 - L2 + L3;
      if (n >= 0 && n < D3) cg[i][k] = su2_cg(L1, i-L1, L2, k-L2, L3, (i-L1)+(k-L2));
    }
  double c[D1][D2][D3] = {};
  double norm2 = 0.0;
  for (int j = 0; j < D1; ++j)
    for (int l = 0; l < D2; ++l)
      for (int m = 0; m < D3; ++m){
        CD s{0.0, 0.0};
        for (int i = 0; i < D1; ++i)
          for (int k = 0; k < D2; ++k){
            double g = cg[i][k];
            if (g == 0.0) continue;
            int n = i + k - L1 - L2 + L3;
            CD t = cmul(q1.m[i][j], q2.m[k][l]);
            t = cmul(t, conj_(q3.m[n][m]));
            s.re += t.re * g; s.im += t.im * g;
          }
        c[j][l][m] = s.re;
        norm2 += s.re * s.re;
      }
  double inv = 1.0 / csqrt_(norm2);
  W3JT<L1,L2,L3> w{};
  for (int j = 0; j < D1; ++j)
    for (int l = 0; l < D2; ++l)
      for (int m = 0; m < D3; ++m){
        double val = c[j][l][m] * inv;
        if (val < 1e-10 && val > -1e-10) val = 0.0;
        w.v[j][l][m] = (float)val;
      }
  return w;
}

// ---------------------------------------------------------------------------
// Path tables (lexicographic e3nn order)
// ---------------------------------------------------------------------------
__device__ __constant__ int L3P_[23]  = {0,1,2,3,1,0,2,1,3,2,2,1,3,0,2,1,3,3,2,1,3,0,2};
// swap = (D1 < D2): MFMA K-dim takes mul1 side, serial loop takes mul2 side
__device__ __constant__ int SWAPP_[23] = {0,1,1,1,0,0,0,1,1,1,0,0,0,0,0,1,1,0,0,0,0,0,0};
// cumulative K3 (2*l3+1) before each path; [23] = 99
constexpr int K3CUM[24] = {0,1,4,9,16,19,20,25,28,35,40,45,48,55,56,61,64,71,78,83,86,93,94,99};
// partial layout per path: idx = K3CUM[p]*131072 + (z*K3p + kk)*64 + w  (w dense)
constexpr size_t PSLICE = 2048ull * 64ull;   // 131072

typedef __bf16 bf16x8 __attribute__((ext_vector_type(8)));
typedef float  f32x4  __attribute__((ext_vector_type(4)));
typedef float  f32x2  __attribute__((ext_vector_type(2)));

// ---------------------------------------------------------------------------
// Prep 1: pack weights fp32 -> bf16 (path coeff folded in), B-fragment order.
// ---------------------------------------------------------------------------
__global__ void pack_w_kernel(const float* __restrict__ w, unsigned short* __restrict__ wp, int total){
  int idx = blockIdx.x * 256 + threadIdx.x;
  if (idx >= total) return;
  int e    = idx & 7;
  int lane = (idx >> 3) & 63;
  int nt   = (idx >> 9) & 3;
  int hf   = (idx >> 11) & 1;
  int s    = (idx >> 12) & 63;
  int p    = idx >> 18;
  int kv = hf*32 + (lane >> 4)*8 + e;
  int wc = nt*16 + (lane & 15);
  int l3 = L3P_[p];
  const float nto[4] = {4.f, 6.f, 7.f, 6.f};
  float coeff = sqrtf((2.f*l3 + 1.f) / (nto[l3] * 4096.f));
  int a = SWAPP_[p] ? kv : s;
  int b = SWAPP_[p] ? s : kv;
  float val = w[(((size_t)p*64 + a)*64 + b)*64 + wc] * coeff;
  unsigned bits = __builtin_bit_cast(unsigned, val);
  unsigned r = (bits + 0x7FFFu + ((bits >> 16) & 1u)) >> 16;   // RNE
  wp[idx] = (unsigned short)r;
}

// ---------------------------------------------------------------------------
// Prep 2: transpose x [2048][1024] -> xT [1024][2048]
// ---------------------------------------------------------------------------
__global__ void transpose_x(const float* __restrict__ x, float* __restrict__ xT){
  __shared__ float t[32][33];
  int bx = blockIdx.x, by = blockIdx.y;
  int tx = threadIdx.x & 31, ty = threadIdx.x >> 5;
  #pragma unroll
  for (int r = 0; r < 4; ++r)
    t[ty + r*8][tx] = x[(size_t)(by*32 + ty + r*8)*1024 + bx*32 + tx];
  __syncthreads();
  #pragma unroll
  for (int r = 0; r < 4; ++r)
    xT[(size_t)(bx*32 + ty + r*8)*2048 + by*32 + tx] = t[tx][ty + r*8];
}

// ---------------------------------------------------------------------------
// NEW STYLE: full-K per wave. Block = 2 independent waves on 2 z-tiles.
// No barriers, no cross-wave reduction. Per kk: 8 chained MFMAs (K=64).
// Epilogue: per-wave LDS transpose (pitch 65) -> 256B-dense partial stores.
// ---------------------------------------------------------------------------
template<int P,int L1,int L2,int L3,bool SWAP,int G0,int G,bool PART>
__device__ __forceinline__ void run_full(
    int tile2, const float* __restrict__ xT,
    const unsigned short* __restrict__ wp,
    float* __restrict__ dst, float* lds)
{
  constexpr int K3 = 2*L3+1;
  constexpr int LK = SWAP ? L1 : L2;
  constexpr int LS = SWAP ? L2 : L1;
  constexpr int DK = 2*LK+1, DS = 2*LS+1;
  constexpr auto C = make_w3j<L1,L2,L3>();

  const int lane = threadIdx.x & 63;
  const int wid  = threadIdx.x >> 6;
  const int z0   = (tile2*2 + wid)*16;
  const int zc   = z0 + (lane & 15);

  // full-K held fragments: lo half (kv 0..31) and hi half (kv 32..63)
  f32x2 xkl[4][DK], xkh[4][DK];
  {
    const float* xkb = xT + (size_t)(64*LK*LK)*2048 + zc;
    const int t0 = (lane >> 4)*8;
    #pragma unroll
    for (int q = 0; q < 4; ++q)
      #pragma unroll
      for (int t = 0; t < DK; ++t){
        xkl[q][t] = f32x2{ xkb[(size_t)((t0 + 2*q    )*DK + t)*2048],
                           xkb[(size_t)((t0 + 2*q + 1)*DK + t)*2048] };
        xkh[q][t] = f32x2{ xkb[(size_t)((32 + t0 + 2*q    )*DK + t)*2048],
                           xkb[(size_t)((32 + t0 + 2*q + 1)*DK + t)*2048] };
      }
  }

  const float* xsp = xT + (size_t)(64*LS*LS)*2048 + zc;
  const unsigned short* wu = wp + (size_t)P*262144 + (size_t)lane*8;

  f32x4 acc[G][4];
  #pragma unroll
  for (int a = 0; a < G; ++a)
    #pragma unroll
    for (int b = 0; b < 4; ++b) acc[a][b] = f32x4{0.f,0.f,0.f,0.f};

  float xs[DS];
  #pragma unroll
  for (int j = 0; j < DS; ++j) xs[j] = xsp[(size_t)j*2048];

  for (int s = 0; s < 64; ++s){
    bf16x8 bl[4], bh[4];
    #pragma unroll
    for (int nt = 0; nt < 4; ++nt){
      bl[nt] = *reinterpret_cast<const bf16x8*>(wu + nt*512);
      bh[nt] = *reinterpret_cast<const bf16x8*>(wu + 2048 + nt*512);
    }
    const float* xnp = (s < 63) ? xsp + (size_t)DS*2048 : xsp;
    float xn[DS];
    #pragma unroll
    for (int j = 0; j < DS; ++j) xn[j] = xnp[(size_t)j*2048];

    #pragma unroll
    for (int kk = 0; kk < G; ++kk){
      float dk[DK];
      #pragma unroll
      for (int t = 0; t < DK; ++t) dk[t] = 0.f;
      #pragma unroll
      for (int t = 0; t < DK; ++t){
        #pragma unroll
        for (int j = 0; j < DS; ++j){
          const float cv = SWAP ? C.v[t][j][G0+kk] : C.v[j][t][G0+kk];
          if (cv != 0.0f) dk[t] = __builtin_fmaf(xs[j], cv, dk[t]);
        }
      }
      f32x2 al2[4], ah2[4];
      #pragma unroll
      for (int q = 0; q < 4; ++q){ al2[q] = f32x2{0.f,0.f}; ah2[q] = f32x2{0.f,0.f}; }
      #pragma unroll
      for (int t = 0; t < DK; ++t){
        const f32x2 d2 = f32x2{dk[t], dk[t]};
        #pragma unroll
        for (int q = 0; q < 4; ++q){
          al2[q] += xkl[q][t] * d2;          // v_pk_fma_f32
          ah2[q] += xkh[q][t] * d2;
        }
      }
      bf16x8 afl, afh;
      #pragma unroll
      for (int q = 0; q < 4; ++q){
        afl[2*q] = (__bf16)al2[q].x;  afl[2*q+1] = (__bf16)al2[q].y;
        afh[2*q] = (__bf16)ah2[q].x;  afh[2*q+1] = (__bf16)ah2[q].y;
      }
      __builtin_amdgcn_s_setprio(1);
      #pragma unroll
      for (int nt = 0; nt < 4; ++nt){
        acc[kk][nt] = __builtin_amdgcn_mfma_f32_16x16x32_bf16(afl, bl[nt], acc[kk][nt], 0, 0, 0);
        acc[kk][nt] = __builtin_amdgcn_mfma_f32_16x16x32_bf16(afh, bh[nt], acc[kk][nt], 0, 0, 0);
      }
      __builtin_amdgcn_s_setprio(0);
    }
    #pragma unroll
    for (int j = 0; j < DS; ++j) xs[j] = xn[j];
    xsp += (size_t)DS*2048;
    wu  += 4096;
  }

  // epilogue: per-wave LDS transpose -> dense [z][kk][w] stores (no barrier:
  // same-wave LDS dependency is ordered by the compiler's lgkmcnt waits)
  if constexpr (PART){
    float* tl = lds + wid*1040;              // 16 rows x 65 pitch
    #pragma unroll
    for (int kk = 0; kk < G; ++kk){
      #pragma unroll
      for (int nt = 0; nt < 4; ++nt)
        #pragma unroll
        for (int r = 0; r < 4; ++r)
          tl[((lane>>4)*4 + r)*65 + nt*16 + (lane & 15)] = acc[kk][nt][r];
      #pragma unroll
      for (int zr = 0; zr < 16; ++zr){
        float v = tl[zr*65 + lane];
        dst[(size_t)K3CUM[P]*PSLICE + ((size_t)(z0 + zr)*K3 + (G0+kk))*64 + lane] = v;
      }
    }
  } else {
    #pragma unroll
    for (int kk = 0; kk < G; ++kk)
      #pragma unroll
      for (int nt = 0; nt < 4; ++nt)
        #pragma unroll
        for (int r = 0; r < 4; ++r){
          int zl = (lane>>4)*4 + r;
          int wc = nt*16 + (lane & 15);
          unsafeAtomicAdd(dst + (size_t)(z0 + zl)*1024 + 64*L3*L3 + wc*K3 + (G0+kk),
                          acc[kk][nt][r]);
        }
  }
}

// ---------------------------------------------------------------------------
// OLD STYLE (DK=7 paths p21/p22 only): 2 waves = K-halves + LDS reduction.
// ---------------------------------------------------------------------------
template<int P,int L1,int L2,int L3,bool SWAP,int G0,int G,bool PART>
__device__ __forceinline__ void run_half(
    int tile, const float* __restrict__ xT,
    const unsigned short* __restrict__ wp,
    float* __restrict__ dst, float* red)
{
  constexpr int K3 = 2*L3+1;
  constexpr int LK = SWAP ? L1 : L2;
  constexpr int LS = SWAP ? L2 : L1;
  constexpr int DK = 2*LK+1, DS = 2*LS+1;
  constexpr auto C = make_w3j<L1,L2,L3>();
  static_assert(G <= 2, "run_half sized for G<=2");

  const int lane = threadIdx.x & 63;
  const int wv   = threadIdx.x >> 6;
  const int zc   = tile*16 + (lane & 15);

  f32x2 xk2[4][DK];
  {
    const float* xkb = xT + (size_t)(64*LK*LK)*2048 + zc;
    const int t0 = wv*32 + (lane >> 4)*8;
    #pragma unroll
    for (int q = 0; q < 4; ++q)
      #pragma unroll
      for (int t = 0; t < DK; ++t)
        xk2[q][t] = f32x2{ xkb[(size_t)((t0 + 2*q    )*DK + t)*2048],
                           xkb[(size_t)((t0 + 2*q + 1)*DK + t)*2048] };
  }

  const float* xsp = xT + (size_t)(64*LS*LS)*2048 + zc;
  const unsigned short* wu = wp + (size_t)P*262144 + (size_t)wv*2048 + (size_t)lane*8;

  f32x4 acc[G][4];
  #pragma unroll
  for (int a = 0; a < G; ++a)
    #pragma unroll
    for (int b = 0; b < 4; ++b) acc[a][b] = f32x4{0.f,0.f,0.f,0.f};

  float xs[DS];
  #pragma unroll
  for (int j = 0; j < DS; ++j) xs[j] = xsp[(size_t)j*2048];

  for (int s = 0; s < 64; ++s){
    bf16x8 bfrag[4];
    #pragma unroll
    for (int nt = 0; nt < 4; ++nt)
      bfrag[nt] = *reinterpret_cast<const bf16x8*>(wu + nt*512);

    const float* xnp = (s < 63) ? xsp + (size_t)DS*2048 : xsp;
    float xn[DS];
    #pragma unroll
    for (int j = 0; j < DS; ++j) xn[j] = xnp[(size_t)j*2048];

    #pragma unroll
    for (int kk = 0; kk < G; ++kk){
      float dk[DK];
      #pragma unroll
      for (int t = 0; t < DK; ++t) dk[t] = 0.f;
      #pragma unroll
      for (int t = 0; t < DK; ++t){
        #pragma unroll
        for (int j = 0; j < DS; ++j){
          const float cv = SWAP ? C.v[t][j][G0+kk] : C.v[j][t][G0+kk];
          if (cv != 0.0f) dk[t] = __builtin_fmaf(xs[j], cv, dk[t]);
        }
      }
      f32x2 af2[4];
      #pragma unroll
      for (int q = 0; q < 4; ++q) af2[q] = f32x2{0.f, 0.f};
      #pragma unroll
      for (int t = 0; t < DK; ++t){
        const f32x2 d2 = f32x2{dk[t], dk[t]};
        #pragma unroll
        for (int q = 0; q < 4; ++q)
          af2[q] += xk2[q][t] * d2;
      }
      bf16x8 af;
      #pragma unroll
      for (int q = 0; q < 4; ++q){
        af[2*q]   = (__bf16)af2[q].x;
        af[2*q+1] = (__bf16)af2[q].y;
      }
      __builtin_amdgcn_s_setprio(1);
      #pragma unroll
      for (int nt = 0; nt < 4; ++nt)
        acc[kk][nt] = __builtin_amdgcn_mfma_f32_16x16x32_bf16(af, bfrag[nt], acc[kk][nt], 0, 0, 0);
      __builtin_amdgcn_s_setprio(0);
    }
    #pragma unroll
    for (int j = 0; j < DS; ++j) xs[j] = xn[j];
    xsp += (size_t)DS*2048;
    wu  += 4096;
  }

  auto store_one = [&](int kk, int nt, const f32x4& o, const f32x4& a){
    #pragma unroll
    for (int r = 0; r < 4; ++r){
      int zl = ((lane >> 4) << 2) + r;
      int wc = nt*16 + (lane & 15);
      float val = a[r] + o[r];
      if constexpr (PART){
        dst[(size_t)K3CUM[P]*PSLICE + ((size_t)(tile*16 + zl)*K3 + (G0+kk))*64 + wc] = val;
      } else {
        unsafeAtomicAdd(dst + (size_t)(tile*16 + zl)*1024 + 64*L3*L3 + wc*K3 + (G0+kk), val);
      }
    }
  };

  if (wv == 1){
    #pragma unroll
    for (int nt = 0; nt < 4; ++nt)
      *reinterpret_cast<f32x4*>(&red[(nt*64 + lane)*4]) = acc[0][nt];
  }
  __syncthreads();
  if (wv == 0){
    #pragma unroll
    for (int nt = 0; nt < 4; ++nt){
      f32x4 o = *reinterpret_cast<const f32x4*>(&red[(nt*64 + lane)*4]);
      store_one(0, nt, o, acc[0][nt]);
    }
  }
  if constexpr (G > 1){
    __syncthreads();
    if (wv == 0){
      #pragma unroll
      for (int nt = 0; nt < 4; ++nt)
        *reinterpret_cast<f32x4*>(&red[(nt*64 + lane)*4]) = acc[1][nt];
    }
    __syncthreads();
    if (wv == 1){
      #pragma unroll
      for (int nt = 0; nt < 4; ++nt){
        f32x4 o = *reinterpret_cast<const f32x4*>(&red[(nt*64 + lane)*4]);
        store_one(1, nt, o, acc[1][nt]);
      }
    }
  }
}

// ---------------------------------------------------------------------------
// Fused kernel: blocks [0,512) = old-style fat slots (128 tiles each);
// blocks [512, 512+59*64) = new-style full-K slots (64 double-tiles each).
// ---------------------------------------------------------------------------
template<bool PART>
__global__ __launch_bounds__(128, 3) void tp_main(const float* __restrict__ xT,
    const unsigned short* __restrict__ wp, float* __restrict__ dst)
{
  __shared__ __align__(16) float lds[2080];   // 8320 B: 2x(16x65) / red(>=1024)
  if (blockIdx.x < 512){
    const int fslot = blockIdx.x >> 7;
    const int tile  = blockIdx.x & 127;
    switch (fslot){
      case 0: run_half<22,3,3,2,false,0,2,PART>(tile,xT,wp,dst,lds); break;
      case 1: run_half<22,3,3,2,false,2,2,PART>(tile,xT,wp,dst,lds); break;
      case 2: run_half<22,3,3,2,false,4,1,PART>(tile,xT,wp,dst,lds); break;
      case 3: run_half<21,3,3,0,false,0,1,PART>(tile,xT,wp,dst,lds); break;
      default: break;
    }
    return;
  }
  const int idx   = blockIdx.x - 512;
  const int slot  = idx >> 6;
  const int tile2 = idx & 63;
  switch (slot){
    // DK=5, G=1 (heavy first)
    case 0:  run_full<16,2,3,3,true ,0,1,PART>(tile2,xT,wp,dst,lds); break;
    case 1:  run_full<16,2,3,3,true ,1,1,PART>(tile2,xT,wp,dst,lds); break;
    case 2:  run_full<16,2,3,3,true ,2,1,PART>(tile2,xT,wp,dst,lds); break;
    case 3:  run_full<16,2,3,3,true ,3,1,PART>(tile2,xT,wp,dst,lds); break;
    case 4:  run_full<16,2,3,3,true ,4,1,PART>(tile2,xT,wp,dst,lds); break;
    case 5:  run_full<16,2,3,3,true ,5,1,PART>(tile2,xT,wp,dst,lds); break;
    case 6:  run_full<16,2,3,3,true ,6,1,PART>(tile2,xT,wp,dst,lds); break;
    case 7:  run_full<20,3,2,3,false,0,1,PART>(tile2,xT,wp,dst,lds); break;
    case 8:  run_full<20,3,2,3,false,1,1,PART>(tile2,xT,wp,dst,lds); break;
    case 9:  run_full<20,3,2,3,false,2,1,PART>(tile2,xT,wp,dst,lds); break;
    case 10: run_full<20,3,2,3,false,3,1,PART>(tile2,xT,wp,dst,lds); break;
    case 11: run_full<20,3,2,3,false,4,1,PART>(tile2,xT,wp,dst,lds); break;
    case 12: run_full<20,3,2,3,false,5,1,PART>(tile2,xT,wp,dst,lds); break;
    case 13: run_full<20,3,2,3,false,6,1,PART>(tile2,xT,wp,dst,lds); break;
    case 14: run_full<15,2,3,1,true ,0,1,PART>(tile2,xT,wp,dst,lds); break;
    case 15: run_full<15,2,3,1,true ,1,1,PART>(tile2,xT,wp,dst,lds); break;
    case 16: run_full<15,2,3,1,true ,2,1,PART>(tile2,xT,wp,dst,lds); break;
    case 17: run_full<19,3,2,1,false,0,1,PART>(tile2,xT,wp,dst,lds); break;
    case 18: run_full<19,3,2,1,false,1,1,PART>(tile2,xT,wp,dst,lds); break;
    case 19: run_full<19,3,2,1,false,2,1,PART>(tile2,xT,wp,dst,lds); break;
    case 20: run_full<14,2,2,2,false,0,1,PART>(tile2,xT,wp,dst,lds); break;
    case 21: run_full<14,2,2,2,false,1,1,PART>(tile2,xT,wp,dst,lds); break;
    case 22: run_full<14,2,2,2,false,2,1,PART>(tile2,xT,wp,dst,lds); break;
    case 23: run_full<14,2,2,2,false,3,1,PART>(tile2,xT,wp,dst,lds); break;
    case 24: run_full<14,2,2,2,false,4,1,PART>(tile2,xT,wp,dst,lds); break;
    case 25: run_full<13,2,2,0,false,0,1,PART>(tile2,xT,wp,dst,lds); break;
    // DK=3, G<=2
    case 26: run_full< 8,1,2,3,true ,0,2,PART>(tile2,xT,wp,dst,lds); break;
    case 27: run_full< 8,1,2,3,true ,2,2,PART>(tile2,xT,wp,dst,lds); break;
    case 28: run_full< 8,1,2,3,true ,4,2,PART>(tile2,xT,wp,dst,lds); break;
    case 29: run_full< 8,1,2,3,true ,6,1,PART>(tile2,xT,wp,dst,lds); break;
    case 30: run_full<12,2,1,3,false,0,2,PART>(tile2,xT,wp,dst,lds); break;
    case 31: run_full<12,2,1,3,false,2,2,PART>(tile2,xT,wp,dst,lds); break;
    case 32: run_full<12,2,1,3,false,4,2,PART>(tile2,xT,wp,dst,lds); break;
    case 33: run_full<12,2,1,3,false,6,1,PART>(tile2,xT,wp,dst,lds); break;
    case 34: run_full< 6,1,1,2,false,0,2,PART>(tile2,xT,wp,dst,lds); break;
    case 35: run_full< 6,1,1,2,false,2,2,PART>(tile2,xT,wp,dst,lds); break;
    case 36: run_full< 6,1,1,2,false,4,1,PART>(tile2,xT,wp,dst,lds); break;
    case 37: run_full< 9,1,3,2,true ,0,2,PART>(tile2,xT,wp,dst,lds); break;
    case 38: run_full< 9,1,3,2,true ,2,2,PART>(tile2,xT,wp,dst,lds); break;
    case 39: run_full< 9,1,3,2,true ,4,1,PART>(tile2,xT,wp,dst,lds); break;
    case 40: run_full<18,3,1,2,false,0,2,PART>(tile2,xT,wp,dst,lds); break;
    case 41: run_full<18,3,1,2,false,2,2,PART>(tile2,xT,wp,dst,lds); break;
    case 42: run_full<18,3,1,2,false,4,1,PART>(tile2,xT,wp,dst,lds); break;
    case 43: run_full< 7,1,2,1,true ,0,2,PART>(tile2,xT,wp,dst,lds); break;
    case 44: run_full< 7,1,2,1,true ,2,1,PART>(tile2,xT,wp,dst,lds); break;
    case 45: run_full<11,2,1,1,false,0,2,PART>(tile2,xT,wp,dst,lds); break;
    case 46: run_full<11,2,1,1,false,2,1,PART>(tile2,xT,wp,dst,lds); break;
    case 47: run_full< 5,1,1,0,false,0,1,PART>(tile2,xT,wp,dst,lds); break;
    // DK=1, G<=4
    case 48: run_full< 3,0,3,3,true ,0,4,PART>(tile2,xT,wp,dst,lds); break;
    case 49: run_full< 3,0,3,3,true ,4,3,PART>(tile2,xT,wp,dst,lds); break;
    case 50: run_full<17,3,0,3,false,0,4,PART>(tile2,xT,wp,dst,lds); break;
    case 51: run_full<17,3,0,3,false,4,3,PART>(tile2,xT,wp,dst,lds); break;
    case 52: run_full< 2,0,2,2,true ,0,3,PART>(tile2,xT,wp,dst,lds); break;
    case 53: run_full< 2,0,2,2,true ,3,2,PART>(tile2,xT,wp,dst,lds); break;
    case 54: run_full<10,2,0,2,false,0,3,PART>(tile2,xT,wp,dst,lds); break;
    case 55: run_full<10,2,0,2,false,3,2,PART>(tile2,xT,wp,dst,lds); break;
    case 56: run_full< 1,0,1,1,true ,0,3,PART>(tile2,xT,wp,dst,lds); break;
    case 57: run_full< 4,1,0,1,false,0,3,PART>(tile2,xT,wp,dst,lds); break;
    case 58: run_full< 0,0,0,0,false,0,1,PART>(tile2,xT,wp,dst,lds); break;
    default: break;
  }
}

// ---------------------------------------------------------------------------
// Gather from [z][kk][w] partials: wave-uniform l3, reads 256B-dense.
// ---------------------------------------------------------------------------
__global__ void gather_out(const float* __restrict__ part, float* __restrict__ out){
  const int z = blockIdx.x;                 // 2048 blocks
  const int t = threadIdx.x;                // 256 threads = 4 waves
  const int w = t & 63;
  const int g = t >> 6;                     // wave id == l3
  float* ob = out + (size_t)z*1024;
  auto rd = [&](int p, int K3p, int k){
    return part[(size_t)K3CUM[p]*PSLICE + ((size_t)z*K3p + k)*64 + w];
  };
  if (g == 0){
    ob[w] = rd(0,1,0) + rd(5,1,0) + rd(13,1,0) + rd(21,1,0);
  } else if (g == 1){
    #pragma unroll
    for (int k = 0; k < 3; ++k)
      ob[64 + w*3 + k] = rd(1,3,k) + rd(4,3,k) + rd(7,3,k)
                       + rd(11,3,k) + rd(15,3,k) + rd(19,3,k);
  } else if (g == 2){
    #pragma unroll
    for (int k = 0; k < 5; ++k)
      ob[256 + w*5 + k] = rd(2,5,k) + rd(6,5,k) + rd(9,5,k) + rd(10,5,k)
                        + rd(14,5,k) + rd(18,5,k) + rd(22,5,k);
  } else {
    #pragma unroll
    for (int k = 0; k < 7; ++k)
      ob[576 + w*7 + k] = rd(3,7,k) + rd(8,7,k) + rd(12,7,k)
                        + rd(16,7,k) + rd(17,7,k) + rd(20,7,k);
  }
}

// ---------------------------------------------------------------------------
extern "C" void kernel_launch(void* const* d_in, const int* in_sizes, int n_in,
                              void* d_out, int out_size, void* d_ws, size_t ws_size,
                              hipStream_t stream)
{
  const float* x = (const float*)d_in[0];        // [2,1024,1024] fp32
  const float* w = (const float*)d_in[1];        // [23,64,64,64] fp32
  float* out = (float*)d_out;                    // [2,1024,1024] fp32

  const size_t packB = 23ull*64*2*4*64*8 * sizeof(unsigned short);   // 12,058,624
  const size_t xTB   = 1024ull*2048*sizeof(float);                   //  8,388,608
  const size_t partB = 99ull*PSLICE*sizeof(float);                   // 51,904,512
  const int totalW = 23*64*2*4*64*8;

  unsigned short* wp = (unsigned short*)d_ws;
  float* xT   = (float*)((char*)d_ws + packB);
  float* part = (float*)((char*)d_ws + packB + xTB);

  if (ws_size < packB + xTB) return;

  pack_w_kernel<<<(totalW + 255)/256, 256, 0, stream>>>(w, wp, totalW);
  dim3 tg(32, 64);
  transpose_x<<<tg, 256, 0, stream>>>(x, xT);

  const int nblocks = 512 + 59*64;   // 4288
  if (ws_size >= packB + xTB + partB){
    tp_main<true><<<nblocks, 128, 0, stream>>>(xT, wp, part);
    gather_out<<<2048, 256, 0, stream>>>(part, out);
  } else {
    hipMemsetAsync(d_out, 0, (size_t)out_size * sizeof(float), stream);
    tp_main<false><<<nblocks, 128, 0, stream>>>(xT, wp, out);
  }
}

// Round 12
// 198.696 us; speedup vs baseline: 1.1498x; 1.1498x over previous
//
#include <hip/hip_runtime.h>

// ---------------------------------------------------------------------------
// Compile-time Wigner 3j (exact port of the reference Python, fp64)
// ---------------------------------------------------------------------------
struct CD { double re, im; };
constexpr CD cmul(CD a, CD b){ return CD{a.re*b.re - a.im*b.im, a.re*b.im + a.im*b.re}; }
constexpr CD conj_(CD a){ return CD{a.re, -a.im}; }

constexpr double factd(int n){ double r = 1.0; for(int i = 2; i <= n; ++i) r *= (double)i; return r; }
constexpr double csqrt_(double x){
  if (x <= 0.0) return 0.0;
  double g = x > 1.0 ? x : 1.0;
  for (int i = 0; i < 100; ++i) g = 0.5*(g + x/g);
  return g;
}

constexpr double su2_cg(int j1,int m1,int j2,int m2,int j3,int m3){
  if (m3 != m1 + m2) return 0.0;
  int vmin = -j1 + j2 + m3;
  if (-j1 + m1 > vmin) vmin = -j1 + m1;
  if (0 > vmin) vmin = 0;
  int vmax = j2 + j3 + m1;
  if (j3 - j1 + j2 < vmax) vmax = j3 - j1 + j2;
  if (j3 + m3 < vmax) vmax = j3 + m3;
  double c = csqrt_((2.0*j3 + 1.0) * factd(j3 + j1 - j2) * factd(j3 - j1 + j2) * factd(j1 + j2 - j3)
                    * factd(j3 + m3) * factd(j3 - m3)
                    / (factd(j1 + j2 + j3 + 1) * factd(j1 - m1) * factd(j1 + m1)
                       * factd(j2 - m2) * factd(j2 + m2)));
  double s = 0.0;
  for (int v = vmin; v <= vmax; ++v){
    double t = (((v + j2 + m2) & 1) ? -1.0 : 1.0) / factd(v)
               * factd(j2 + j3 + m1 - v) * factd(j1 - m1 + v)
               / factd(j3 - j1 + j2 - v) / factd(j3 + m3 - v) / factd(v + j1 - j2 - m3);
    s += t;
  }
  return c * s;
}

struct QM { CD m[7][7]; };
constexpr QM qmat(int l){
  QM q{};
  double is2 = 1.0 / csqrt_(2.0);
  for (int mm = -l; mm < 0; ++mm){
    q.m[l+mm][l-mm] = CD{is2, 0.0};
    q.m[l+mm][l+mm] = CD{0.0, -is2};
  }
  q.m[l][l] = CD{1.0, 0.0};
  for (int mm = 1; mm <= l; ++mm){
    double sgn = (mm & 1) ? -1.0 : 1.0;
    q.m[l+mm][l+mm] = CD{sgn*is2, 0.0};
    q.m[l+mm][l-mm] = CD{0.0, sgn*is2};
  }
  CD ph = (l % 4 == 0) ? CD{1,0} : (l % 4 == 1) ? CD{0,-1} : (l % 4 == 2) ? CD{-1,0} : CD{0,1};
  for (int r = 0; r < 7; ++r)
    for (int c = 0; c < 7; ++c)
      q.m[r][c] = cmul(ph, q.m[r][c]);
  return q;
}

template<int L1,int L2,int L3> struct W3JT { float v[2*L1+1][2*L2+1][2*L3+1]; };

template<int L1,int L2,int L3>
constexpr W3JT<L1,L2,L3> make_w3j(){
  constexpr int D1 = 2*L1+1, D2 = 2*L2+1, D3 = 2*L3+1;
  QM q1 = qmat(L1), q2 = qmat(L2), q3 = qmat(L3);
  double cg[7][7] = {};
  for (int i = 0; i < D1; ++i)
    for (int k = 0; k < D2; ++k){
      int n = i + k - L1 - L2 + L3;
      if (n >= 0 && n < D3) cg[i][k] = su2_cg(L1, i-L1, L2, k-L2, L3, (i-L1)+(k-L2));
    }
  double c[D1][D2][D3] = {};
  double norm2 = 0.0;
  for (int j = 0; j < D1; ++j)
    for (int l = 0; l < D2; ++l)
      for (int m = 0; m < D3; ++m){
        CD s{0.0, 0.0};
        for (int i = 0; i < D1; ++i)
          for (int k = 0; k < D2; ++k){
            double g = cg[i][k];
            if (g == 0.0) continue;
            int n = i + k - L1 - L2 + L3;
            CD t = cmul(q1.m[i][j], q2.m[k][l]);
            t = cmul(t, conj_(q3.m[n][m]));
            s.re += t.re * g; s.im += t.im * g;
          }
        c[j][l][m] = s.re;
        norm2 += s.re * s.re;
      }
  double inv = 1.0 / csqrt_(norm2);
  W3JT<L1,L2,L3> w{};
  for (int j = 0; j < D1; ++j)
    for (int l = 0; l < D2; ++l)
      for (int m = 0; m < D3; ++m){
        double val = c[j][l][m] * inv;
        if (val < 1e-10 && val > -1e-10) val = 0.0;
        w.v[j][l][m] = (float)val;
      }
  return w;
}

// ---------------------------------------------------------------------------
// Path tables (lexicographic e3nn order)
// ---------------------------------------------------------------------------
__device__ __constant__ int L3P_[23]  = {0,1,2,3,1,0,2,1,3,2,2,1,3,0,2,1,3,3,2,1,3,0,2};
// swap = (D1 < D2): MFMA K-dim takes mul1 side, serial loop takes mul2 side
__device__ __constant__ int SWAPP_[23] = {0,1,1,1,0,0,0,1,1,1,0,0,0,0,0,1,1,0,0,0,0,0,0};
// cumulative K3 (2*l3+1) before each path; [23] = 99
constexpr int K3CUM[24] = {0,1,4,9,16,19,20,25,28,35,40,45,48,55,56,61,64,71,78,83,86,93,94,99};
// partial layout per path: idx = K3CUM[p]*PSLICE + ((z*K3p + kk)*64 + w)  (w dense)
constexpr size_t PSLICE = 2048ull * 64ull;   // 131072

typedef __bf16 bf16x8 __attribute__((ext_vector_type(8)));
typedef float  f32x4  __attribute__((ext_vector_type(4)));
typedef float  f32x2  __attribute__((ext_vector_type(2)));

// ---------------------------------------------------------------------------
// Prep 1: pack weights fp32 -> bf16 (path coeff folded in), B-fragment order.
// ---------------------------------------------------------------------------
__global__ void pack_w_kernel(const float* __restrict__ w, unsigned short* __restrict__ wp, int total){
  int idx = blockIdx.x * 256 + threadIdx.x;
  if (idx >= total) return;
  int e    = idx & 7;
  int lane = (idx >> 3) & 63;
  int nt   = (idx >> 9) & 3;
  int hf   = (idx >> 11) & 1;
  int s    = (idx >> 12) & 63;
  int p    = idx >> 18;
  int kv = hf*32 + (lane >> 4)*8 + e;
  int wc = nt*16 + (lane & 15);
  int l3 = L3P_[p];
  const float nto[4] = {4.f, 6.f, 7.f, 6.f};
  float coeff = sqrtf((2.f*l3 + 1.f) / (nto[l3] * 4096.f));
  int a = SWAPP_[p] ? kv : s;
  int b = SWAPP_[p] ? s : kv;
  float val = w[(((size_t)p*64 + a)*64 + b)*64 + wc] * coeff;
  unsigned bits = __builtin_bit_cast(unsigned, val);
  unsigned r = (bits + 0x7FFFu + ((bits >> 16) & 1u)) >> 16;   // RNE
  wp[idx] = (unsigned short)r;
}

// ---------------------------------------------------------------------------
// Prep 2: transpose x [2048][1024] -> xT [1024][2048]
// ---------------------------------------------------------------------------
__global__ void transpose_x(const float* __restrict__ x, float* __restrict__ xT){
  __shared__ float t[32][33];
  int bx = blockIdx.x, by = blockIdx.y;
  int tx = threadIdx.x & 31, ty = threadIdx.x >> 5;
  #pragma unroll
  for (int r = 0; r < 4; ++r)
    t[ty + r*8][tx] = x[(size_t)(by*32 + ty + r*8)*1024 + bx*32 + tx];
  __syncthreads();
  #pragma unroll
  for (int r = 0; r < 4; ++r)
    xT[(size_t)(bx*32 + ty + r*8)*2048 + by*32 + tx] = t[tx][ty + r*8];
}

// ---------------------------------------------------------------------------
// Main slot: path P, k3 range [G0,G0+G). SWAP selects which mul feeds MFMA-K.
// 2 waves = K-halves; serial loop over the other mul (64 steps).
// Epilogue: cross-wave reduce via red, then per-wave LDS transpose (pitch 65)
// -> 256B-dense partial stores in [z][kk][w] layout.
// LDS: red[3072] + 2 x 1040 transpose areas = 5152 floats (20.6 KB).
// ---------------------------------------------------------------------------
template<int P,int L1,int L2,int L3,bool SWAP,int G0,int G,bool PART>
__device__ __forceinline__ void run_slot(
    int tile, const float* __restrict__ xT,
    const unsigned short* __restrict__ wp,
    float* __restrict__ dst, float* lds)
{
  constexpr int K3 = 2*L3+1;
  constexpr int LK = SWAP ? L1 : L2;         // angular l of MFMA-K mul
  constexpr int LS = SWAP ? L2 : L1;         // angular l of serial mul
  constexpr int DK = 2*LK+1, DS = 2*LS+1;
  constexpr auto C = make_w3j<L1,L2,L3>();

  const int lane = threadIdx.x & 63;
  const int wv   = threadIdx.x >> 6;         // K-half
  const int zc   = tile*16 + (lane & 15);    // A row (z)
  float* red = lds;                          // [3072]
  float* tl  = lds + 3072 + wv*1040;         // per-wave 16 x 65 transpose area

  // held fragment: 4 e-pairs x DK angular, packed f32x2
  f32x2 xk2[4][DK];
  {
    const float* xkb = xT + (size_t)(64*LK*LK)*2048 + zc;
    const int t0 = wv*32 + (lane >> 4)*8;
    #pragma unroll
    for (int q = 0; q < 4; ++q)
      #pragma unroll
      for (int t = 0; t < DK; ++t){
        float lo = xkb[(size_t)((t0 + 2*q    )*DK + t)*2048];
        float hi = xkb[(size_t)((t0 + 2*q + 1)*DK + t)*2048];
        xk2[q][t] = f32x2{lo, hi};
      }
  }

  const float* xsp = xT + (size_t)(64*LS*LS)*2048 + zc;
  const unsigned short* wu = wp + (size_t)P*262144 + (size_t)wv*2048 + (size_t)lane*8;

  f32x4 acc[G][4];
  #pragma unroll
  for (int a = 0; a < G; ++a)
    #pragma unroll
    for (int b = 0; b < 4; ++b) acc[a][b] = f32x4{0.f,0.f,0.f,0.f};

  // software-prefetched serial-x
  float xs[DS];
  #pragma unroll
  for (int j = 0; j < DS; ++j) xs[j] = xsp[(size_t)j*2048];

  for (int s = 0; s < 64; ++s){
    bf16x8 bfrag[4];
    #pragma unroll
    for (int nt = 0; nt < 4; ++nt)
      bfrag[nt] = *reinterpret_cast<const bf16x8*>(wu + nt*512);

    const float* xnp = (s < 63) ? xsp + (size_t)DS*2048 : xsp;
    float xn[DS];
    #pragma unroll
    for (int j = 0; j < DS; ++j) xn[j] = xnp[(size_t)j*2048];

    #pragma unroll
    for (int kk = 0; kk < G; ++kk){
      float dk[DK];
      #pragma unroll
      for (int t = 0; t < DK; ++t) dk[t] = 0.f;
      #pragma unroll
      for (int t = 0; t < DK; ++t){
        #pragma unroll
        for (int j = 0; j < DS; ++j){
          const float cv = SWAP ? C.v[t][j][G0+kk] : C.v[j][t][G0+kk];
          if (cv != 0.0f) dk[t] = __builtin_fmaf(xs[j], cv, dk[t]);
        }
      }
      // af via packed f32x2 FMA
      f32x2 af2[4];
      #pragma unroll
      for (int q = 0; q < 4; ++q) af2[q] = f32x2{0.f, 0.f};
      #pragma unroll
      for (int t = 0; t < DK; ++t){
        const f32x2 d2 = f32x2{dk[t], dk[t]};
        #pragma unroll
        for (int q = 0; q < 4; ++q)
          af2[q] += xk2[q][t] * d2;          // -> v_pk_fma_f32
      }
      bf16x8 af;
      #pragma unroll
      for (int q = 0; q < 4; ++q){
        af[2*q]   = (__bf16)af2[q].x;
        af[2*q+1] = (__bf16)af2[q].y;
      }
      __builtin_amdgcn_s_setprio(1);
      #pragma unroll
      for (int nt = 0; nt < 4; ++nt)
        acc[kk][nt] = __builtin_amdgcn_mfma_f32_16x16x32_bf16(af, bfrag[nt], acc[kk][nt], 0, 0, 0);
      __builtin_amdgcn_s_setprio(0);
    }
    #pragma unroll
    for (int j = 0; j < DS; ++j) xs[j] = xn[j];
    xsp += (size_t)DS*2048;
    wu  += 4096;
  }

  // two-phase cross-wave reduction (red), both waves store half the kks.
  // Per stored kk: per-wave LDS transpose -> dense [z][kk][w] global stores.
  constexpr int Gh = (G + 1) / 2;
  static_assert(Gh <= 3, "red[] sized for Gh<=3");
  auto store_kk = [&](int kk, const f32x4 (&sum)[4]){
    if constexpr (PART){
      // transpose within the wave: no barrier needed (same-wave LDS order)
      #pragma unroll
      for (int nt = 0; nt < 4; ++nt)
        #pragma unroll
        for (int r = 0; r < 4; ++r)
          tl[(((lane >> 4)*4 + r))*65 + nt*16 + (lane & 15)] = sum[nt][r];
      #pragma unroll
      for (int zr = 0; zr < 16; ++zr){
        float v = tl[zr*65 + lane];
        dst[(size_t)K3CUM[P]*PSLICE + ((size_t)(tile*16 + zr)*K3 + (G0+kk))*64 + lane] = v;
      }
    } else {
      #pragma unroll
      for (int nt = 0; nt < 4; ++nt)
        #pragma unroll
        for (int r = 0; r < 4; ++r){
          int zl = ((lane >> 4) << 2) + r;
          int wc = nt*16 + (lane & 15);
          unsafeAtomicAdd(dst + (size_t)(tile*16 + zl)*1024 + 64*L3*L3 + wc*K3 + (G0+kk),
                          sum[nt][r]);
        }
    }
  };

  if (wv == 1){
    #pragma unroll
    for (int kk = 0; kk < Gh; ++kk)
      #pragma unroll
      for (int nt = 0; nt < 4; ++nt)
        *reinterpret_cast<f32x4*>(&red[((kk*4 + nt)*64 + lane)*4]) = acc[kk][nt];
  }
  __syncthreads();
  if (wv == 0){
    #pragma unroll
    for (int kk = 0; kk < Gh; ++kk){
      f32x4 sum[4];
      #pragma unroll
      for (int nt = 0; nt < 4; ++nt){
        f32x4 o = *reinterpret_cast<const f32x4*>(&red[((kk*4 + nt)*64 + lane)*4]);
        sum[nt] = acc[kk][nt] + o;
      }
      store_kk(kk, sum);
    }
  }
  if constexpr (G > Gh){
    if (wv == 0){
      #pragma unroll
      for (int kk = Gh; kk < G; ++kk)
        #pragma unroll
        for (int nt = 0; nt < 4; ++nt)
          *reinterpret_cast<f32x4*>(&red[(((kk-Gh)*4 + nt)*64 + lane)*4]) = acc[kk][nt];
    }
    __syncthreads();
    if (wv == 1){
      #pragma unroll
      for (int kk = Gh; kk < G; ++kk){
        f32x4 sum[4];
        #pragma unroll
        for (int nt = 0; nt < 4; ++nt){
          f32x4 o = *reinterpret_cast<const f32x4*>(&red[(((kk-Gh)*4 + nt)*64 + lane)*4]);
          sum[nt] = acc[kk][nt] + o;
        }
        store_kk(kk, sum);
      }
    }
  }
}

template<bool PART>
__global__ __launch_bounds__(128, 3) void tp_main(const float* __restrict__ xT,
    const unsigned short* __restrict__ wp, float* __restrict__ dst)
{
  __shared__ __align__(16) float lds[5152];   // red 3072 + 2 x 1040 transpose
  const int slot = blockIdx.x >> 7;
  const int tile = blockIdx.x & 127;
  switch (slot){
    // 36 slots, heavy-first; every branch sized for no spills under (128,3).
    case 0:  run_slot< 6,1,1,2,false,0,5,PART>(tile,xT,wp,dst,lds); break;
    case 1:  run_slot<16,2,3,3,true ,0,3,PART>(tile,xT,wp,dst,lds); break;
    case 2:  run_slot<20,3,2,3,false,0,3,PART>(tile,xT,wp,dst,lds); break;
    case 3:  run_slot<14,2,2,2,false,0,3,PART>(tile,xT,wp,dst,lds); break;
    case 4:  run_slot<15,2,3,1,true ,0,3,PART>(tile,xT,wp,dst,lds); break;
    case 5:  run_slot<19,3,2,1,false,0,3,PART>(tile,xT,wp,dst,lds); break;
    case 6:  run_slot< 8,1,2,3,true ,0,4,PART>(tile,xT,wp,dst,lds); break;
    case 7:  run_slot<12,2,1,3,false,0,4,PART>(tile,xT,wp,dst,lds); break;
    case 8:  run_slot<22,3,3,2,false,0,2,PART>(tile,xT,wp,dst,lds); break;
    case 9:  run_slot<22,3,3,2,false,2,2,PART>(tile,xT,wp,dst,lds); break;
    case 10: run_slot< 9,1,3,2,true ,0,3,PART>(tile,xT,wp,dst,lds); break;
    case 11: run_slot<16,2,3,3,true ,3,2,PART>(tile,xT,wp,dst,lds); break;
    case 12: run_slot<16,2,3,3,true ,5,2,PART>(tile,xT,wp,dst,lds); break;
    case 13: run_slot<20,3,2,3,false,3,2,PART>(tile,xT,wp,dst,lds); break;
    case 14: run_slot<20,3,2,3,false,5,2,PART>(tile,xT,wp,dst,lds); break;
    case 15: run_slot< 2,0,2,2,true ,0,5,PART>(tile,xT,wp,dst,lds); break;
    case 16: run_slot<10,2,0,2,false,0,5,PART>(tile,xT,wp,dst,lds); break;
    case 17: run_slot<11,2,1,1,false,0,3,PART>(tile,xT,wp,dst,lds); break;
    case 18: run_slot< 7,1,2,1,true ,0,3,PART>(tile,xT,wp,dst,lds); break;
    case 19: run_slot<18,3,1,2,false,0,3,PART>(tile,xT,wp,dst,lds); break;
    case 20: run_slot< 8,1,2,3,true ,4,3,PART>(tile,xT,wp,dst,lds); break;
    case 21: run_slot<12,2,1,3,false,4,3,PART>(tile,xT,wp,dst,lds); break;
    case 22: run_slot<14,2,2,2,false,3,2,PART>(tile,xT,wp,dst,lds); break;
    case 23: run_slot< 9,1,3,2,true ,3,2,PART>(tile,xT,wp,dst,lds); break;
    case 24: run_slot<18,3,1,2,false,3,2,PART>(tile,xT,wp,dst,lds); break;
    case 25: run_slot<22,3,3,2,false,4,1,PART>(tile,xT,wp,dst,lds); break;
    case 26: run_slot<21,3,3,0,false,0,1,PART>(tile,xT,wp,dst,lds); break;
    case 27: run_slot< 3,0,3,3,true ,0,4,PART>(tile,xT,wp,dst,lds); break;
    case 28: run_slot<17,3,0,3,false,0,4,PART>(tile,xT,wp,dst,lds); break;
    case 29: run_slot< 3,0,3,3,true ,4,3,PART>(tile,xT,wp,dst,lds); break;
    case 30: run_slot<17,3,0,3,false,4,3,PART>(tile,xT,wp,dst,lds); break;
    case 31: run_slot< 1,0,1,1,true ,0,3,PART>(tile,xT,wp,dst,lds); break;
    case 32: run_slot< 4,1,0,1,false,0,3,PART>(tile,xT,wp,dst,lds); break;
    case 33: run_slot<13,2,2,0,false,0,1,PART>(tile,xT,wp,dst,lds); break;
    case 34: run_slot< 5,1,1,0,false,0,1,PART>(tile,xT,wp,dst,lds); break;
    case 35: run_slot< 0,0,0,0,false,0,1,PART>(tile,xT,wp,dst,lds); break;
    default: break;
  }
}

// ---------------------------------------------------------------------------
// Gather from [z][kk][w] partials: wave-uniform l3, reads 256B-dense.
// ---------------------------------------------------------------------------
__global__ void gather_out(const float* __restrict__ part, float* __restrict__ out){
  const int z = blockIdx.x;                 // 2048 blocks
  const int t = threadIdx.x;                // 256 threads = 4 waves
  const int w = t & 63;
  const int g = t >> 6;                     // wave id == l3
  float* ob = out + (size_t)z*1024;
  auto rd = [&](int p, int K3p, int k){
    return part[(size_t)K3CUM[p]*PSLICE + ((size_t)z*K3p + k)*64 + w];
  };
  if (g == 0){
    ob[w] = rd(0,1,0) + rd(5,1,0) + rd(13,1,0) + rd(21,1,0);
  } else if (g == 1){
    #pragma unroll
    for (int k = 0; k < 3; ++k)
      ob[64 + w*3 + k] = rd(1,3,k) + rd(4,3,k) + rd(7,3,k)
                       + rd(11,3,k) + rd(15,3,k) + rd(19,3,k);
  } else if (g == 2){
    #pragma unroll
    for (int k = 0; k < 5; ++k)
      ob[256 + w*5 + k] = rd(2,5,k) + rd(6,5,k) + rd(9,5,k) + rd(10,5,k)
                        + rd(14,5,k) + rd(18,5,k) + rd(22,5,k);
  } else {
    #pragma unroll
    for (int k = 0; k < 7; ++k)
      ob[576 + w*7 + k] = rd(3,7,k) + rd(8,7,k) + rd(12,7,k)
                        + rd(16,7,k) + rd(17,7,k) + rd(20,7,k);
  }
}

// ---------------------------------------------------------------------------
extern "C" void kernel_launch(void* const* d_in, const int* in_sizes, int n_in,
                              void* d_out, int out_size, void* d_ws, size_t ws_size,
                              hipStream_t stream)
{
  const float* x = (const float*)d_in[0];        // [2,1024,1024] fp32
  const float* w = (const float*)d_in[1];        // [23,64,64,64] fp32
  float* out = (float*)d_out;                    // [2,1024,1024] fp32

  const size_t packB = 23ull*64*2*4*64*8 * sizeof(unsigned short);   // 12,058,624
  const size_t xTB   = 1024ull*2048*sizeof(float);                   //  8,388,608
  const size_t partB = 99ull*PSLICE*sizeof(float);                   // 51,904,512
  const int totalW = 23*64*2*4*64*8;

  unsigned short* wp = (unsigned short*)d_ws;
  float* xT   = (float*)((char*)d_ws + packB);
  float* part = (float*)((char*)d_ws + packB + xTB);

  if (ws_size < packB + xTB) return;

  pack_w_kernel<<<(totalW + 255)/256, 256, 0, stream>>>(w, wp, totalW);
  dim3 tg(32, 64);
  transpose_x<<<tg, 256, 0, stream>>>(x, xT);

  if (ws_size >= packB + xTB + partB){
    tp_main<true><<<36*128, 128, 0, stream>>>(xT, wp, part);
    gather_out<<<2048, 256, 0, stream>>>(part, out);
  } else {
    hipMemsetAsync(d_out, 0, (size_t)out_size * sizeof(float), stream);
    tp_main<false><<<36*128, 128, 0, stream>>>(xT, wp, out);
  }
}